// Round 1
// baseline (62.075 us; speedup 1.0000x reference)
//
#include <hip/hip_runtime.h>

#define N_ROWS 8192
#define D_IN 512
#define EMBED 256
#define NBLK 256   // blocks for the streaming passes; 32 rows/block, 8 rows/wave

// ---------------------------------------------------------------------------
// K1: w_v[d] = sum_e head_w[e] * W_V[e][d]      (512 outputs)
// ---------------------------------------------------------------------------
__global__ __launch_bounds__(512) void k_wv(const float* __restrict__ W_V,
                                            const float* __restrict__ head_w,
                                            float* __restrict__ wv) {
    int d = threadIdx.x;  // 512 threads, one block
    float acc = 0.f;
#pragma unroll 8
    for (int e = 0; e < EMBED; ++e) acc += head_w[e] * W_V[e * D_IN + d];
    wv[d] = acc;
}

// ---------------------------------------------------------------------------
// K2: for each row i: s_i = x_i . w_v ; accumulate t += s_i * x_i
// Deterministic: per-block partial t vectors written to ws, no atomics.
// Layout: wave w of block b handles rows b*32 + w*8 .. +7.
// Lane l owns columns [l*4, l*4+4) and [256 + l*4, 256 + l*4 + 4).
// ---------------------------------------------------------------------------
__global__ __launch_bounds__(256) void k_pass1(const float* __restrict__ X,
                                               const float* __restrict__ wv,
                                               float* __restrict__ partials) {
    const int tid  = threadIdx.x;
    const int lane = tid & 63;
    const int wid  = tid >> 6;       // 0..3
    const int c0   = lane * 4;
    const int c1   = 256 + lane * 4;

    const float4 wv0 = *(const float4*)(wv + c0);
    const float4 wv1 = *(const float4*)(wv + c1);

    float4 t0 = {0.f, 0.f, 0.f, 0.f};
    float4 t1 = {0.f, 0.f, 0.f, 0.f};

    const int row0 = blockIdx.x * 32 + wid * 8;
#pragma unroll
    for (int r = 0; r < 8; ++r) {
        const float* xr = X + (size_t)(row0 + r) * D_IN;
        const float4 a = *(const float4*)(xr + c0);
        const float4 b = *(const float4*)(xr + c1);
        float p = a.x * wv0.x + a.y * wv0.y + a.z * wv0.z + a.w * wv0.w
                + b.x * wv1.x + b.y * wv1.y + b.z * wv1.z + b.w * wv1.w;
#pragma unroll
        for (int off = 32; off >= 1; off >>= 1) p += __shfl_xor(p, off, 64);
        // p == s_i broadcast to all lanes; rank-1 accumulate
        t0.x += p * a.x; t0.y += p * a.y; t0.z += p * a.z; t0.w += p * a.w;
        t1.x += p * b.x; t1.y += p * b.y; t1.z += p * b.z; t1.w += p * b.w;
    }

    __shared__ float lds[4][D_IN];
    *(float4*)(&lds[wid][c0]) = t0;
    *(float4*)(&lds[wid][c1]) = t1;
    __syncthreads();

    for (int col = tid; col < D_IN; col += 256) {
        float s = lds[0][col] + lds[1][col] + lds[2][col] + lds[3][col];
        partials[(size_t)blockIdx.x * D_IN + col] = s;
    }
}

// ---------------------------------------------------------------------------
// K3 (1 block, 512 threads): t = sum_b partials[b]; u = W_K t; r = W_Q^T u
// ---------------------------------------------------------------------------
__global__ __launch_bounds__(512) void k_mid(const float* __restrict__ partials,
                                             const float* __restrict__ W_K,
                                             const float* __restrict__ W_Q,
                                             float* __restrict__ r_out) {
    __shared__ float t_lds[D_IN];
    __shared__ float u_lds[EMBED];
    const int tid = threadIdx.x;

    // t[d]
    float acc = 0.f;
    for (int b = 0; b < NBLK; ++b) acc += partials[(size_t)b * D_IN + tid];
    t_lds[tid] = acc;
    __syncthreads();

    // u[e] = W_K[e,:] . t
    if (tid < EMBED) {
        float ua = 0.f;
        const float* wk = W_K + (size_t)tid * D_IN;
#pragma unroll 8
        for (int d = 0; d < D_IN; ++d) ua += wk[d] * t_lds[d];
        u_lds[tid] = ua;
    }
    __syncthreads();

    // r[d] = sum_e W_Q[e,d] * u[e]
    float ra = 0.f;
#pragma unroll 8
    for (int e = 0; e < EMBED; ++e) ra += W_Q[(size_t)e * D_IN + tid] * u_lds[e];
    r_out[tid] = ra;
}

// ---------------------------------------------------------------------------
// K4: preds[i] = x_i . r + head_b
// ---------------------------------------------------------------------------
__global__ __launch_bounds__(256) void k_pass2(const float* __restrict__ X,
                                               const float* __restrict__ r,
                                               const float* __restrict__ head_b,
                                               float* __restrict__ out) {
    const int tid  = threadIdx.x;
    const int lane = tid & 63;
    const int wid  = tid >> 6;
    const int c0   = lane * 4;
    const int c1   = 256 + lane * 4;

    const float4 r0 = *(const float4*)(r + c0);
    const float4 r1 = *(const float4*)(r + c1);
    const float bb  = head_b[0];

    const int row0 = blockIdx.x * 32 + wid * 8;
#pragma unroll
    for (int rr = 0; rr < 8; ++rr) {
        const int row = row0 + rr;
        const float* xr = X + (size_t)row * D_IN;
        const float4 a = *(const float4*)(xr + c0);
        const float4 b = *(const float4*)(xr + c1);
        float p = a.x * r0.x + a.y * r0.y + a.z * r0.z + a.w * r0.w
                + b.x * r1.x + b.y * r1.y + b.z * r1.z + b.w * r1.w;
#pragma unroll
        for (int off = 32; off >= 1; off >>= 1) p += __shfl_xor(p, off, 64);
        if (lane == 0) out[row] = p + bb;
    }
}

// ---------------------------------------------------------------------------
extern "C" void kernel_launch(void* const* d_in, const int* in_sizes, int n_in,
                              void* d_out, int out_size, void* d_ws, size_t ws_size,
                              hipStream_t stream) {
    const float* X      = (const float*)d_in[0];
    const float* W_Q    = (const float*)d_in[1];
    const float* W_K    = (const float*)d_in[2];
    const float* W_V    = (const float*)d_in[3];
    const float* head_w = (const float*)d_in[4];
    const float* head_b = (const float*)d_in[5];
    float* out = (float*)d_out;

    float* ws       = (float*)d_ws;
    float* wv       = ws;            // 512 floats
    float* r        = ws + 512;      // 512 floats
    float* partials = ws + 1024;     // NBLK * 512 floats = 512 KB

    k_wv   <<<1,    512, 0, stream>>>(W_V, head_w, wv);
    k_pass1<<<NBLK, 256, 0, stream>>>(X, wv, partials);
    k_mid  <<<1,    512, 0, stream>>>(partials, W_K, W_Q, r);
    k_pass2<<<NBLK, 256, 0, stream>>>(X, r, head_b, out);
}

// Round 2
// 28.784 us; speedup vs baseline: 2.1566x; 2.1566x over previous
//
#include <hip/hip_runtime.h>

#define N_ROWS 8192
#define D_IN 512
#define EMBED 256
#define NBLK 256   // streaming blocks; 32 rows/block, 8 rows/wave

// ws layout (floats):
//   wvp      @ 0       : 4*512   (w_v partials, 4 e-chunks)
//   rp       @ 2048    : 4*512   (r partials, 4 e-chunks)
//   u        @ 4096    : 256
//   t16      @ 4608    : 16*512  (t partials, 16 p-chunks)
//   partials @ 16384   : 256*512 (per-pass1-block t partials)
#define WS_WVP   0
#define WS_RP    2048
#define WS_U     4096
#define WS_T16   4608
#define WS_PART  16384

// ---------------------------------------------------------------------------
// K1: wvp[eg][d] = sum_{e in chunk eg} head_w[e] * W_V[e][d]
// grid 32 = 8 col-groups x 4 e-chunks, 64 threads
// ---------------------------------------------------------------------------
__global__ __launch_bounds__(64) void k_wv(const float* __restrict__ W_V,
                                           const float* __restrict__ head_w,
                                           float* __restrict__ wvp) {
    const int cg = blockIdx.x & 7;
    const int eg = blockIdx.x >> 3;
    const int col = cg * 64 + threadIdx.x;
    float acc = 0.f;
    const int e0 = eg * 64;
#pragma unroll 8
    for (int e = e0; e < e0 + 64; ++e) acc += head_w[e] * W_V[(size_t)e * D_IN + col];
    wvp[(size_t)eg * D_IN + col] = acc;
}

// ---------------------------------------------------------------------------
// K2: per row i: s_i = x_i . w_v ; per-block t partial -> partials[b][:]
// ---------------------------------------------------------------------------
__global__ __launch_bounds__(256) void k_pass1(const float* __restrict__ X,
                                               const float* __restrict__ wvp,
                                               float* __restrict__ partials) {
    const int tid  = threadIdx.x;
    const int lane = tid & 63;
    const int wid  = tid >> 6;       // 0..3
    const int c0   = lane * 4;
    const int c1   = 256 + lane * 4;

    float4 wv0 = {0.f,0.f,0.f,0.f}, wv1 = {0.f,0.f,0.f,0.f};
#pragma unroll
    for (int eg = 0; eg < 4; ++eg) {
        const float4 a = *(const float4*)(wvp + (size_t)eg * D_IN + c0);
        const float4 b = *(const float4*)(wvp + (size_t)eg * D_IN + c1);
        wv0.x += a.x; wv0.y += a.y; wv0.z += a.z; wv0.w += a.w;
        wv1.x += b.x; wv1.y += b.y; wv1.z += b.z; wv1.w += b.w;
    }

    float4 t0 = {0.f,0.f,0.f,0.f};
    float4 t1 = {0.f,0.f,0.f,0.f};

    const int row0 = blockIdx.x * 32 + wid * 8;
#pragma unroll
    for (int r = 0; r < 8; ++r) {
        const float* xr = X + (size_t)(row0 + r) * D_IN;
        const float4 a = *(const float4*)(xr + c0);
        const float4 b = *(const float4*)(xr + c1);
        float p = a.x * wv0.x + a.y * wv0.y + a.z * wv0.z + a.w * wv0.w
                + b.x * wv1.x + b.y * wv1.y + b.z * wv1.z + b.w * wv1.w;
#pragma unroll
        for (int off = 32; off >= 1; off >>= 1) p += __shfl_xor(p, off, 64);
        t0.x += p * a.x; t0.y += p * a.y; t0.z += p * a.z; t0.w += p * a.w;
        t1.x += p * b.x; t1.y += p * b.y; t1.z += p * b.z; t1.w += p * b.w;
    }

    __shared__ float lds[4][D_IN];
    *(float4*)(&lds[wid][c0]) = t0;
    *(float4*)(&lds[wid][c1]) = t1;
    __syncthreads();

    for (int col = tid; col < D_IN; col += 256) {
        float s = lds[0][col] + lds[1][col] + lds[2][col] + lds[3][col];
        partials[(size_t)blockIdx.x * D_IN + col] = s;
    }
}

// ---------------------------------------------------------------------------
// K3: t16[b][col] = sum_{p in [16b,16b+16)} partials[p][col]
// grid 16 x 256 threads; fully coalesced 1KB wave loads
// ---------------------------------------------------------------------------
__global__ __launch_bounds__(256) void k_tred(const float* __restrict__ partials,
                                              float* __restrict__ t16) {
    const int tid = threadIdx.x;
    const int p0  = blockIdx.x * 16;
    float a0 = 0.f, a1 = 0.f;
#pragma unroll
    for (int p = p0; p < p0 + 16; ++p) {
        a0 += partials[(size_t)p * D_IN + tid];
        a1 += partials[(size_t)p * D_IN + 256 + tid];
    }
    t16[(size_t)blockIdx.x * D_IN + tid]       = a0;
    t16[(size_t)blockIdx.x * D_IN + 256 + tid] = a1;
}

// ---------------------------------------------------------------------------
// K4: u[e] = W_K[e,:] . t,  t = sum of 16 t16 rows.  Wave per e.
// grid 64 x 256 threads (4 waves)
// ---------------------------------------------------------------------------
__global__ __launch_bounds__(256) void k_u(const float* __restrict__ t16,
                                           const float* __restrict__ W_K,
                                           float* __restrict__ u) {
    const int lane = threadIdx.x & 63;
    const int wid  = threadIdx.x >> 6;
    const int e    = blockIdx.x * 4 + wid;
    const int c0   = lane * 4;
    const int c1   = 256 + lane * 4;

    float4 tA = {0.f,0.f,0.f,0.f}, tB = {0.f,0.f,0.f,0.f};
#pragma unroll
    for (int j = 0; j < 16; ++j) {
        const float4 a = *(const float4*)(t16 + (size_t)j * D_IN + c0);
        const float4 b = *(const float4*)(t16 + (size_t)j * D_IN + c1);
        tA.x += a.x; tA.y += a.y; tA.z += a.z; tA.w += a.w;
        tB.x += b.x; tB.y += b.y; tB.z += b.z; tB.w += b.w;
    }
    const float4 wA = *(const float4*)(W_K + (size_t)e * D_IN + c0);
    const float4 wB = *(const float4*)(W_K + (size_t)e * D_IN + c1);
    float p = tA.x * wA.x + tA.y * wA.y + tA.z * wA.z + tA.w * wA.w
            + tB.x * wB.x + tB.y * wB.y + tB.z * wB.z + tB.w * wB.w;
#pragma unroll
    for (int off = 32; off >= 1; off >>= 1) p += __shfl_xor(p, off, 64);
    if (lane == 0) u[e] = p;
}

// ---------------------------------------------------------------------------
// K5: rp[eg][d] = sum_{e in chunk eg} W_Q[e][d] * u[e]
// grid 32 = 8 col-groups x 4 e-chunks, 64 threads
// ---------------------------------------------------------------------------
__global__ __launch_bounds__(64) void k_r(const float* __restrict__ W_Q,
                                          const float* __restrict__ u,
                                          float* __restrict__ rp) {
    const int cg = blockIdx.x & 7;
    const int eg = blockIdx.x >> 3;
    const int col = cg * 64 + threadIdx.x;
    float acc = 0.f;
    const int e0 = eg * 64;
#pragma unroll 8
    for (int e = e0; e < e0 + 64; ++e) acc += u[e] * W_Q[(size_t)e * D_IN + col];
    rp[(size_t)eg * D_IN + col] = acc;
}

// ---------------------------------------------------------------------------
// K6: preds[i] = x_i . r + head_b,  r = sum of 4 rp rows
// ---------------------------------------------------------------------------
__global__ __launch_bounds__(256) void k_pass2(const float* __restrict__ X,
                                               const float* __restrict__ rp,
                                               const float* __restrict__ head_b,
                                               float* __restrict__ out) {
    const int tid  = threadIdx.x;
    const int lane = tid & 63;
    const int wid  = tid >> 6;
    const int c0   = lane * 4;
    const int c1   = 256 + lane * 4;

    float4 r0 = {0.f,0.f,0.f,0.f}, r1 = {0.f,0.f,0.f,0.f};
#pragma unroll
    for (int eg = 0; eg < 4; ++eg) {
        const float4 a = *(const float4*)(rp + (size_t)eg * D_IN + c0);
        const float4 b = *(const float4*)(rp + (size_t)eg * D_IN + c1);
        r0.x += a.x; r0.y += a.y; r0.z += a.z; r0.w += a.w;
        r1.x += b.x; r1.y += b.y; r1.z += b.z; r1.w += b.w;
    }
    const float bb = head_b[0];

    const int row0 = blockIdx.x * 32 + wid * 8;
#pragma unroll
    for (int rr = 0; rr < 8; ++rr) {
        const int row = row0 + rr;
        const float* xr = X + (size_t)row * D_IN;
        const float4 a = *(const float4*)(xr + c0);
        const float4 b = *(const float4*)(xr + c1);
        float p = a.x * r0.x + a.y * r0.y + a.z * r0.z + a.w * r0.w
                + b.x * r1.x + b.y * r1.y + b.z * r1.z + b.w * r1.w;
#pragma unroll
        for (int off = 32; off >= 1; off >>= 1) p += __shfl_xor(p, off, 64);
        if (lane == 0) out[row] = p + bb;
    }
}

// ---------------------------------------------------------------------------
extern "C" void kernel_launch(void* const* d_in, const int* in_sizes, int n_in,
                              void* d_out, int out_size, void* d_ws, size_t ws_size,
                              hipStream_t stream) {
    const float* X      = (const float*)d_in[0];
    const float* W_Q    = (const float*)d_in[1];
    const float* W_K    = (const float*)d_in[2];
    const float* W_V    = (const float*)d_in[3];
    const float* head_w = (const float*)d_in[4];
    const float* head_b = (const float*)d_in[5];
    float* out = (float*)d_out;

    float* ws       = (float*)d_ws;
    float* wvp      = ws + WS_WVP;
    float* rp       = ws + WS_RP;
    float* u        = ws + WS_U;
    float* t16      = ws + WS_T16;
    float* partials = ws + WS_PART;

    k_wv   <<<32,   64,  0, stream>>>(W_V, head_w, wvp);
    k_pass1<<<NBLK, 256, 0, stream>>>(X, wvp, partials);
    k_tred <<<16,   256, 0, stream>>>(partials, t16);
    k_u    <<<64,   256, 0, stream>>>(t16, W_K, u);
    k_r    <<<32,   64,  0, stream>>>(W_Q, u, rp);
    k_pass2<<<NBLK, 256, 0, stream>>>(X, rp, head_b, out);
}

// Round 3
// 26.391 us; speedup vs baseline: 2.3522x; 1.0907x over previous
//
#include <hip/hip_runtime.h>

#define D_IN 512
#define EMBED 256
#define NBLK1 256              // streaming blocks; 32 rows/block, 4 rows/wave
#define SCALE 16777216.0f      // 2^24
#define INV_SCALE 5.9604644775390625e-08f  // 2^-24

// ws byte layout:
//   wvp     @ 0     : float[4][512]            (8 KB)   w_v partials, 4 e-chunks
//   t_fixed @ 8192  : ull[8][512]              (32 KB)  fixed-point t, 8 copies
//   r_fixed @ 40960 : ull[4][512]              (16 KB)  fixed-point r, 4 copies
#define WS_WVP_B 0
#define WS_TFX_B 8192
#define WS_RFX_B 40960
#define N_ZERO   6144          // 4096 + 2048 ull entries, contiguous

typedef unsigned long long ull;

// ---------------------------------------------------------------------------
// K1: wvp[eg][d] = sum_{e in chunk eg} head_w[e]*W_V[e][d]; also zero atomics.
// grid 32 = 8 col-groups x 4 e-chunks, 64 threads
// ---------------------------------------------------------------------------
__global__ __launch_bounds__(64) void k_wv(const float* __restrict__ W_V,
                                           const float* __restrict__ head_w,
                                           float* __restrict__ wvp,
                                           ull* __restrict__ zbase) {
    const int cg  = blockIdx.x & 7;
    const int eg  = blockIdx.x >> 3;
    const int col = cg * 64 + threadIdx.x;
    float acc = 0.f;
    const int e0 = eg * 64;
#pragma unroll 8
    for (int e = e0; e < e0 + 64; ++e) acc += head_w[e] * W_V[(size_t)e * D_IN + col];
    wvp[(size_t)eg * D_IN + col] = acc;

    // zero t_fixed + r_fixed (contiguous 6144 ulls) — runs before pass1/k_ur
    const int g = blockIdx.x * 64 + threadIdx.x;
    for (int i = g; i < N_ZERO; i += 32 * 64) zbase[i] = 0ull;
}

// ---------------------------------------------------------------------------
// K2: per row i: s_i = x_i . wv ; block-reduce t-partial in LDS; one int64
// atomicAdd per column into t_fixed[blk&7][:].  256 blocks x 512 threads.
// ---------------------------------------------------------------------------
__global__ __launch_bounds__(512) void k_pass1(const float* __restrict__ X,
                                               const float* __restrict__ wvp,
                                               ull* __restrict__ t_fixed) {
    const int tid  = threadIdx.x;
    const int lane = tid & 63;
    const int wid  = tid >> 6;       // 0..7
    const int c0   = lane * 4;
    const int c1   = 256 + lane * 4;

    float4 wv0 = {0.f,0.f,0.f,0.f}, wv1 = {0.f,0.f,0.f,0.f};
#pragma unroll
    for (int eg = 0; eg < 4; ++eg) {
        const float4 a = *(const float4*)(wvp + (size_t)eg * D_IN + c0);
        const float4 b = *(const float4*)(wvp + (size_t)eg * D_IN + c1);
        wv0.x += a.x; wv0.y += a.y; wv0.z += a.z; wv0.w += a.w;
        wv1.x += b.x; wv1.y += b.y; wv1.z += b.z; wv1.w += b.w;
    }

    float4 t0 = {0.f,0.f,0.f,0.f};
    float4 t1 = {0.f,0.f,0.f,0.f};

    const int row0 = blockIdx.x * 32 + wid * 4;
#pragma unroll
    for (int r = 0; r < 4; ++r) {
        const float* xr = X + (size_t)(row0 + r) * D_IN;
        const float4 a = *(const float4*)(xr + c0);
        const float4 b = *(const float4*)(xr + c1);
        float p = a.x * wv0.x + a.y * wv0.y + a.z * wv0.z + a.w * wv0.w
                + b.x * wv1.x + b.y * wv1.y + b.z * wv1.z + b.w * wv1.w;
#pragma unroll
        for (int off = 32; off >= 1; off >>= 1) p += __shfl_xor(p, off, 64);
        t0.x += p * a.x; t0.y += p * a.y; t0.z += p * a.z; t0.w += p * a.w;
        t1.x += p * b.x; t1.y += p * b.y; t1.z += p * b.z; t1.w += p * b.w;
    }

    __shared__ float lds[8][D_IN];
    *(float4*)(&lds[wid][c0]) = t0;
    *(float4*)(&lds[wid][c1]) = t1;
    __syncthreads();

    // 512 threads: one column each; fixed-point atomic into 1-of-8 copies
    float s = 0.f;
#pragma unroll
    for (int w = 0; w < 8; ++w) s += lds[w][tid];
    const long long v = llrintf(s * SCALE);
    atomicAdd(&t_fixed[(size_t)(blockIdx.x & 7) * D_IN + tid], (ull)v);
}

// ---------------------------------------------------------------------------
// K3: t = sum of 8 fixed copies; wave w computes u[e]=W_K[e,:].t for
// e = blk*8+w; immediately scatters u[e]*W_Q[e,:] into r_fixed[blk&3][:].
// grid 32 x 512 threads.
// ---------------------------------------------------------------------------
__global__ __launch_bounds__(512) void k_ur(const ull* __restrict__ t_fixed,
                                            const float* __restrict__ W_K,
                                            const float* __restrict__ W_Q,
                                            ull* __restrict__ r_fixed) {
    __shared__ float t_lds[D_IN];
    const int tid = threadIdx.x;

    long long acc = 0;
#pragma unroll
    for (int j = 0; j < 8; ++j) acc += (long long)t_fixed[(size_t)j * D_IN + tid];
    t_lds[tid] = (float)acc * INV_SCALE;
    __syncthreads();

    const int lane = tid & 63;
    const int w    = tid >> 6;
    const int e    = blockIdx.x * 8 + w;
    const int c0   = lane * 4;
    const int c1   = 256 + lane * 4;

    const float4 ta = *(const float4*)(t_lds + c0);
    const float4 tb = *(const float4*)(t_lds + c1);
    const float4 ka = *(const float4*)(W_K + (size_t)e * D_IN + c0);
    const float4 kb = *(const float4*)(W_K + (size_t)e * D_IN + c1);
    float p = ta.x * ka.x + ta.y * ka.y + ta.z * ka.z + ta.w * ka.w
            + tb.x * kb.x + tb.y * kb.y + tb.z * kb.z + tb.w * kb.w;
#pragma unroll
    for (int off = 32; off >= 1; off >>= 1) p += __shfl_xor(p, off, 64);
    // p == u[e] in every lane

    const float4 qa = *(const float4*)(W_Q + (size_t)e * D_IN + c0);
    const float4 qb = *(const float4*)(W_Q + (size_t)e * D_IN + c1);
    ull* rr = r_fixed + (size_t)(blockIdx.x & 3) * D_IN;
    atomicAdd(&rr[c0 + 0], (ull)(long long)llrintf(p * qa.x * SCALE));
    atomicAdd(&rr[c0 + 1], (ull)(long long)llrintf(p * qa.y * SCALE));
    atomicAdd(&rr[c0 + 2], (ull)(long long)llrintf(p * qa.z * SCALE));
    atomicAdd(&rr[c0 + 3], (ull)(long long)llrintf(p * qa.w * SCALE));
    atomicAdd(&rr[c1 + 0], (ull)(long long)llrintf(p * qb.x * SCALE));
    atomicAdd(&rr[c1 + 1], (ull)(long long)llrintf(p * qb.y * SCALE));
    atomicAdd(&rr[c1 + 2], (ull)(long long)llrintf(p * qb.z * SCALE));
    atomicAdd(&rr[c1 + 3], (ull)(long long)llrintf(p * qb.w * SCALE));
}

// ---------------------------------------------------------------------------
// K4: r = sum of 4 fixed copies (LDS prelude); preds[i] = x_i . r + head_b.
// 256 blocks x 512 threads, 4 rows/wave.
// ---------------------------------------------------------------------------
__global__ __launch_bounds__(512) void k_pass2(const float* __restrict__ X,
                                               const ull* __restrict__ r_fixed,
                                               const float* __restrict__ head_b,
                                               float* __restrict__ out) {
    __shared__ float r_lds[D_IN];
    const int tid = threadIdx.x;

    long long acc = 0;
#pragma unroll
    for (int j = 0; j < 4; ++j) acc += (long long)r_fixed[(size_t)j * D_IN + tid];
    r_lds[tid] = (float)acc * INV_SCALE;
    __syncthreads();

    const int lane = tid & 63;
    const int wid  = tid >> 6;
    const int c0   = lane * 4;
    const int c1   = 256 + lane * 4;

    const float4 r0 = *(const float4*)(r_lds + c0);
    const float4 r1 = *(const float4*)(r_lds + c1);
    const float bb  = head_b[0];

    const int row0 = blockIdx.x * 32 + wid * 4;
#pragma unroll
    for (int rr = 0; rr < 4; ++rr) {
        const int row = row0 + rr;
        const float* xr = X + (size_t)row * D_IN;
        const float4 a = *(const float4*)(xr + c0);
        const float4 b = *(const float4*)(xr + c1);
        float p = a.x * r0.x + a.y * r0.y + a.z * r0.z + a.w * r0.w
                + b.x * r1.x + b.y * r1.y + b.z * r1.z + b.w * r1.w;
#pragma unroll
        for (int off = 32; off >= 1; off >>= 1) p += __shfl_xor(p, off, 64);
        if (lane == 0) out[row] = p + bb;
    }
}

// ---------------------------------------------------------------------------
extern "C" void kernel_launch(void* const* d_in, const int* in_sizes, int n_in,
                              void* d_out, int out_size, void* d_ws, size_t ws_size,
                              hipStream_t stream) {
    const float* X      = (const float*)d_in[0];
    const float* W_Q    = (const float*)d_in[1];
    const float* W_K    = (const float*)d_in[2];
    const float* W_V    = (const float*)d_in[3];
    const float* head_w = (const float*)d_in[4];
    const float* head_b = (const float*)d_in[5];
    float* out = (float*)d_out;

    char* ws = (char*)d_ws;
    float* wvp    = (float*)(ws + WS_WVP_B);
    ull*   t_fix  = (ull*)  (ws + WS_TFX_B);
    ull*   r_fix  = (ull*)  (ws + WS_RFX_B);

    k_wv   <<<32,    64, 0, stream>>>(W_V, head_w, wvp, t_fix);  // zbase == t_fix
    k_pass1<<<NBLK1, 512, 0, stream>>>(X, wvp, t_fix);
    k_ur   <<<32,   512, 0, stream>>>(t_fix, W_K, W_Q, r_fix);
    k_pass2<<<NBLK1, 512, 0, stream>>>(X, r_fix, head_b, out);
}